// Round 11
// baseline (685.986 us; speedup 1.0000x reference)
//
#include <hip/hip_runtime.h>
#include <hip/hip_bf16.h>

#define N_NODES 200000
#define N_EDGES 4000000
#define R_REL   4
#define D_DIM   64
#define G_GRAPHS 64
#define C_CLS   10
#define NR      (N_NODES * R_REL)      // 800000
#define POOL_BLOCKS 128

// 2-pass radix CSR build
#define NCB   391                       // ceil(NR / 2048) coarse buckets (key>>11)
#define LCAP  64                        // LDS bin cap (lambda=20.9, +9.3 sigma)
#define CCAP  11264                     // coarse bucket cap (lambda=10230, +10 sigma)
#define EPB   8192                      // edges per k_coarse block (512 thr x 16)

#define EMBED_BLOCKS 12500              // N*16/256
#define BOUNDS_BLOCKS 782               // ceil(N/256)

typedef __attribute__((ext_vector_type(8))) short short8v;   // 8 bf16 (4 VGPR)
typedef __attribute__((ext_vector_type(4))) float f32x4;

__device__ __forceinline__ unsigned short to_bf16(float x) {
    __hip_bfloat16 b = __float2bfloat16(x);
    return *(unsigned short*)&b;
}

#define ACC8(u) \
    a0 += __uint_as_float((u).x << 16); \
    a1 += __uint_as_float((u).x & 0xFFFF0000u); \
    a2 += __uint_as_float((u).y << 16); \
    a3 += __uint_as_float((u).y & 0xFFFF0000u); \
    a4 += __uint_as_float((u).z << 16); \
    a5 += __uint_as_float((u).z & 0xFFFF0000u); \
    a6 += __uint_as_float((u).w << 16); \
    a7 += __uint_as_float((u).w & 0xFFFF0000u);

// ---------------- CSR build pass 1: LDS-staged coarse binning ----------------
// entry = (key & 2047) << 18 | src   (11 + 18 bits)

__global__ __launch_bounds__(512) void k_coarse(
    const int* __restrict__ src, const int* __restrict__ tgt,
    const int* __restrict__ et,
    int* __restrict__ gcur, unsigned int* __restrict__ coarse) {
    __shared__ unsigned int bins[NCB * LCAP];   // 100 KB
    __shared__ int lcnt[NCB], lpos[NCB];

    const int tid = threadIdx.x;
    for (int i = tid; i < NCB; i += 512) lcnt[i] = 0;
    __syncthreads();

#pragma unroll
    for (int h = 0; h < 4; ++h) {
        int e4 = blockIdx.x * EPB + (h * 512 + tid) * 4;
        if (e4 < N_EDGES) {
            int4 s = *(const int4*)&src[e4];
            int4 t = *(const int4*)&tgt[e4];
            int4 r = *(const int4*)&et[e4];
#define PUT(ss, tt, rr) { \
                int key = (tt) * R_REL + (rr); \
                int b = key >> 11; \
                int p = atomicAdd(&lcnt[b], 1); \
                if (p < LCAP) bins[b * LCAP + p] = \
                    ((unsigned int)(key & 2047) << 18) | (unsigned int)(ss); \
            }
            PUT(s.x, t.x, r.x); PUT(s.y, t.y, r.y);
            PUT(s.z, t.z, r.z); PUT(s.w, t.w, r.w);
#undef PUT
        }
    }
    __syncthreads();

    for (int i = tid; i < NCB; i += 512) {
        int c = lcnt[i]; if (c > LCAP) c = LCAP;
        lcnt[i] = c;
        lpos[i] = atomicAdd(&gcur[i], c);
    }
    __syncthreads();

    for (int j = tid; j < NCB * LCAP; j += 512) {
        int b = j >> 6, l = j & 63;
        if (l < lcnt[b]) {
            int gp = lpos[b] + l;
            if (gp < CCAP) coarse[(size_t)b * CCAP + gp] = bins[j];
        }
    }
}

// ---------------- CSR build pass 2: per-bucket fine counting sort ----------------
// Inline 512-wide scan over coarse bucket totals replaces the old serial k_cscan.

__global__ __launch_bounds__(1024) void k_fine(
    const int* __restrict__ gcur, const unsigned int* __restrict__ coarse,
    int* __restrict__ off, int* __restrict__ srcSorted) {
    __shared__ unsigned int ent[CCAP];   // 45 KB
    __shared__ int hist[2048];           // 8 KB
    __shared__ int pre[512];             // 2 KB

    const int cb = blockIdx.x, tid = threadIdx.x;

    // inclusive scan of clamped gcur over 512 slots -> base for this bucket
    int v = 0;
    if (tid < 512) {
        v = (tid < NCB) ? gcur[tid] : 0;
        if (v > CCAP) v = CCAP;
        pre[tid] = v;
    }
    __syncthreads();
    for (int d = 1; d < 512; d <<= 1) {
        int t = 0;
        if (tid < 512 && tid >= d) t = pre[tid - d];
        __syncthreads();
        if (tid < 512) pre[tid] += t;
        __syncthreads();
    }
    const int gb = (cb > 0) ? pre[cb - 1] : 0;

    int cnt = gcur[cb]; if (cnt > CCAP) cnt = CCAP;
    const int key0 = cb << 11;
    const unsigned int* cp = coarse + (size_t)cb * CCAP;

    for (int i = tid; i < cnt; i += 1024) ent[i] = cp[i];
    hist[tid] = 0; hist[tid + 1024] = 0;
    __syncthreads();

    for (int i = tid; i < cnt; i += 1024) atomicAdd(&hist[ent[i] >> 18], 1);
    __syncthreads();

    int x0 = hist[tid], x1 = hist[tid + 1024];
    for (int d = 1; d < 2048; d <<= 1) {
        int v0 = (tid >= d) ? hist[tid - d] : 0;
        int v1 = hist[tid + 1024 - d];
        __syncthreads();
        hist[tid] += v0;
        hist[tid + 1024] += v1;
        __syncthreads();
    }
    int excl0 = hist[tid] - x0;
    int excl1 = hist[tid + 1024] - x1;
    __syncthreads();
    hist[tid] = excl0;                   // becomes scatter cursor
    hist[tid + 1024] = excl1;

    int key = key0 + tid;
    if (key < NR) off[key] = gb + excl0;
    key = key0 + tid + 1024;
    if (key < NR) off[key] = gb + excl1;
    if (cb == NCB - 1 && tid == 0) off[NR] = N_EDGES;
    __syncthreads();

    for (int i = tid; i < cnt; i += 1024) {
        unsigned int e = ent[i];
        int pos = atomicAdd(&hist[e >> 18], 1);
        srcSorted[gb + pos] = (int)(e & 0x3FFFFu);
    }
}

// ---------------- degree-bucketed key permutation (3 passes) ----------------
// class = min(deg, 15); perm groups equal-class keys so k_agg waves have
// uniform segment lengths (kills exec-mask divergence).

__global__ void k_dhist(const int* __restrict__ off, int* __restrict__ ghist,
                        int* __restrict__ blockBase) {
    __shared__ int h[16];
    int tid = threadIdx.x;
    if (tid < 16) h[tid] = 0;
    __syncthreads();
    int k0 = blockIdx.x * 2048 + tid * 8;
#pragma unroll
    for (int i = 0; i < 8; ++i) {
        int k = k0 + i;
        if (k < NR) {
            int d = off[k + 1] - off[k];
            if (d > 15) d = 15;
            atomicAdd(&h[d], 1);
        }
    }
    __syncthreads();
    if (tid < 16) blockBase[blockIdx.x * 16 + tid] = atomicAdd(&ghist[tid], h[tid]);
}

__global__ void k_dscan(const int* __restrict__ ghist, int* __restrict__ classBase) {
    if (threadIdx.x == 0) {
        int a = 0;
        for (int c = 0; c < 16; ++c) { classBase[c] = a; a += ghist[c]; }
    }
}

__global__ void k_dperm(const int* __restrict__ off, const int* __restrict__ classBase,
                        const int* __restrict__ blockBase, int* __restrict__ perm) {
    __shared__ int cur[16];
    int tid = threadIdx.x;
    if (tid < 16) cur[tid] = classBase[tid] + blockBase[blockIdx.x * 16 + tid];
    __syncthreads();
    int k0 = blockIdx.x * 2048 + tid * 8;
#pragma unroll
    for (int i = 0; i < 8; ++i) {
        int k = k0 + i;
        if (k < NR) {
            int d = off[k + 1] - off[k];
            if (d > 15) d = 15;
            int pos = atomicAdd(&cur[d], 1);
            perm[pos] = k;
        }
    }
}

// ---------------- fused misc: embed + bounds + weight prep ----------------

struct WPtrs { const float* p[15]; };

__global__ void k_misc(const int* __restrict__ xop, const int* __restrict__ xcat,
                       const float4* __restrict__ opemb, const float4* __restrict__ catemb,
                       ushort4* __restrict__ hb,
                       const int* __restrict__ batch, int* __restrict__ start,
                       WPtrs wp, unsigned short* __restrict__ wfrag) {
    int bid = blockIdx.x;
    if (bid < EMBED_BLOCKS) {
        int i = bid * 256 + threadIdx.x;
        if (i < N_NODES * 16) {
            int n = i >> 4, q = i & 15;
            float4 a = opemb[xop[n] * 16 + q];
            float4 b = catemb[xcat[n] * 16 + q];
            ushort4 ub;
            ub.x = to_bf16(a.x + b.x); ub.y = to_bf16(a.y + b.y);
            ub.z = to_bf16(a.z + b.z); ub.w = to_bf16(a.w + b.w);
            hb[i] = ub;
        }
    } else if (bid < EMBED_BLOCKS + BOUNDS_BLOCKS) {
        int i = (bid - EMBED_BLOCKS) * 256 + threadIdx.x;
        if (i >= N_NODES) return;
        int b = batch[i];
        if (i == 0) {
            for (int g = 0; g <= b; ++g) start[g] = 0;
        } else {
            int p = batch[i - 1];
            for (int g = p + 1; g <= b; ++g) start[g] = i;
        }
        if (i == N_NODES - 1) {
            for (int g = b + 1; g <= G_GRAPHS; ++g) start[g] = N_NODES;
        }
    } else {
        int m = bid - EMBED_BLOCKS - BOUNDS_BLOCKS;    // 0..14
        const float* W = wp.p[m];
        unsigned short* outp = wfrag + m * 4096;
        for (int f = threadIdx.x; f < 4096; f += 256) {
            int j = f & 7, lane = (f >> 3) & 63, c0t = (f >> 9) & 3, kk = f >> 11;
            int k  = kk * 32 + (lane >> 4) * 8 + j;
            int ch = c0t * 16 + (lane & 15);
            outp[f] = to_bf16(W[k * 64 + ch]);
        }
    }
}

// ---------------- phase A: per-key mean aggregation (degree-scheduled) ----------------

__global__ __launch_bounds__(256) void k_agg(
    const unsigned short* __restrict__ hb_in,   // [N][64] bf16
    const int* __restrict__ off,
    const int* __restrict__ srcSorted,
    const int* __restrict__ perm,
    unsigned short* __restrict__ m_out)         // [R][N][64] bf16 means (rel-major)
{
    const int wave = (blockIdx.x * 256 + threadIdx.x) >> 6;
    const int lane = threadIdx.x & 63;
    const int g = lane >> 3, q = lane & 7;
    const int key = perm[wave * 8 + g];         // grid sized so idx < NR

    const int e0 = off[key];
    const int e1 = off[key + 1];

    float a0 = 0.f, a1 = 0.f, a2 = 0.f, a3 = 0.f,
          a4 = 0.f, a5 = 0.f, a6 = 0.f, a7 = 0.f;

    const unsigned short* base = hb_in + q * 8;

    int e = e0;
    for (; e + 4 <= e1; e += 4) {
        int s0 = srcSorted[e];
        int s1 = srcSorted[e + 1];
        int s2 = srcSorted[e + 2];
        int s3 = srcSorted[e + 3];
        uint4 u0 = *(const uint4*)(base + (size_t)s0 * D_DIM);
        uint4 u1 = *(const uint4*)(base + (size_t)s1 * D_DIM);
        uint4 u2 = *(const uint4*)(base + (size_t)s2 * D_DIM);
        uint4 u3 = *(const uint4*)(base + (size_t)s3 * D_DIM);
        ACC8(u0); ACC8(u1); ACC8(u2); ACC8(u3);
    }
    for (; e < e1; ++e) {
        int s0 = srcSorted[e];
        uint4 u0 = *(const uint4*)(base + (size_t)s0 * D_DIM);
        ACC8(u0);
    }

    int deg = e1 - e0;
    const float iv = 1.0f / (float)(deg > 0 ? deg : 1);
    uint4 o;
    o.x = (unsigned int)to_bf16(a0 * iv) | ((unsigned int)to_bf16(a1 * iv) << 16);
    o.y = (unsigned int)to_bf16(a2 * iv) | ((unsigned int)to_bf16(a3 * iv) << 16);
    o.z = (unsigned int)to_bf16(a4 * iv) | ((unsigned int)to_bf16(a5 * iv) << 16);
    o.w = (unsigned int)to_bf16(a6 * iv) | ((unsigned int)to_bf16(a7 * iv) << 16);
    const int node = key >> 2, r = key & 3;
    *(uint4*)(m_out + ((size_t)r * N_NODES + node) * D_DIM + q * 8) = o;
}

// ---------------- phase B: MFMA 16x16x32 bf16 GEMM ----------------

template <int RELU>
__global__ __launch_bounds__(1024) void k_trans(
    const unsigned short* __restrict__ hb_in,  // [N][64] bf16 (root pass)
    const unsigned short* __restrict__ m_in,   // [R][N][64] bf16 means (rel-major)
    unsigned short* __restrict__ hb_out,       // [N][64] bf16
    const unsigned short* __restrict__ wfrag,  // this layer: [5][2][4][64][8] bf16
    const float* __restrict__ bias)            // [64]
{
    __shared__ unsigned short wf[5 * 4096];    // 40 KB

    const int tid = threadIdx.x;
    for (int i = tid; i < 2560; i += 1024)
        ((uint4*)wf)[i] = ((const uint4*)wfrag)[i];
    __syncthreads();

    const int lane = tid & 63, wid = tid >> 6;
    const int n0 = blockIdx.x * 64 + (wid >> 2) * 16;   // node base of wave-tile
    const int c0 = (wid & 3) * 16;                      // out-ch base
    const int arow = n0 + (lane & 15);
    const int koff = (lane >> 4) * 8;                   // element offset (bf16)

    f32x4 acc = {0.f, 0.f, 0.f, 0.f};

#pragma unroll
    for (int r = 0; r < 5; ++r) {
        const unsigned short* asrc = (r < 4)
            ? (m_in + ((size_t)r * N_NODES + arow) * D_DIM)
            : (hb_in + (size_t)arow * D_DIM);
        uint4 a0u = *(const uint4*)(asrc + koff);        // k block 0..31
        uint4 a1u = *(const uint4*)(asrc + 32 + koff);   // k block 32..63
        const unsigned short* bbase = wf + r * 4096 + (wid & 3) * 512 + lane * 8;
        uint4 b0u = *(const uint4*)bbase;                // kk=0
        uint4 b1u = *(const uint4*)(bbase + 2048);       // kk=1
        acc = __builtin_amdgcn_mfma_f32_16x16x32_bf16(
            __builtin_bit_cast(short8v, a0u), __builtin_bit_cast(short8v, b0u), acc, 0, 0, 0);
        acc = __builtin_amdgcn_mfma_f32_16x16x32_bf16(
            __builtin_bit_cast(short8v, a1u), __builtin_bit_cast(short8v, b1u), acc, 0, 0, 0);
    }

    float bv = bias[c0 + (lane & 15)];
#pragma unroll
    for (int i = 0; i < 4; ++i) {
        float v = acc[i] + bv;
        if (RELU) v = fmaxf(v, 0.f);
        int n = n0 + (lane >> 4) * 4 + i;
        hb_out[(size_t)n * D_DIM + c0 + (lane & 15)] = to_bf16(v);
    }
}

// ---------------- pooling: run-accumulated (batch is sorted), bf16 input ----------------

__global__ __launch_bounds__(1024) void k_pool(const unsigned short* __restrict__ hb,
                                               const int* __restrict__ batch,
                                               float* __restrict__ partial) {
    __shared__ float bin[G_GRAPHS * D_DIM];   // 16 KB
    int tid = threadIdx.x, lane = tid & 63, wid = tid >> 6;
    for (int i = tid; i < G_GRAPHS * D_DIM; i += 1024) bin[i] = 0.f;
    __syncthreads();
    const int per = (N_NODES + POOL_BLOCKS - 1) / POOL_BLOCKS;
    int n0 = blockIdx.x * per;
    int n1 = n0 + per; if (n1 > N_NODES) n1 = N_NODES;
    int cntw = n1 - n0;
    int sub = (cntw + 15) >> 4;
    int w0 = n0 + wid * sub;
    int w1 = w0 + sub; if (w1 > n1) w1 = n1;

    float acc = 0.f;
    int cur = -1;
    for (int n = w0; n < w1; ++n) {
        int b = __builtin_amdgcn_readfirstlane(batch[n]);
        unsigned int u = hb[(size_t)n * D_DIM + lane];
        float v = __uint_as_float(u << 16);
        if (b != cur) {
            if (cur >= 0) atomicAdd(&bin[cur * D_DIM + lane], acc);
            cur = b;
            acc = v;
        } else {
            acc += v;
        }
    }
    if (cur >= 0) atomicAdd(&bin[cur * D_DIM + lane], acc);
    __syncthreads();
    for (int i = tid; i < G_GRAPHS * D_DIM; i += 1024)
        partial[blockIdx.x * (G_GRAPHS * D_DIM) + i] = bin[i];
}

__global__ void k_pool_reduce(const float* __restrict__ partial,
                              float* __restrict__ pooled) {
    int i = blockIdx.x * blockDim.x + threadIdx.x;   // 4096
    if (i < G_GRAPHS * D_DIM) {
        float s = 0.f;
        for (int b = 0; b < POOL_BLOCKS; ++b) s += partial[b * (G_GRAPHS * D_DIM) + i];
        pooled[i] = s;
    }
}

// ---------------- head ----------------

__global__ void k_head(const float* __restrict__ pooled, const int* __restrict__ start,
                       const float* __restrict__ fc1w, const float* __restrict__ fc1b,
                       const float* __restrict__ fc2w, const float* __restrict__ fc2b,
                       float* __restrict__ out) {
    __shared__ float p[G_GRAPHS][D_DIM];
    __shared__ float hf[G_GRAPHS][D_DIM];
    __shared__ float sc[G_GRAPHS][C_CLS];
    int t = threadIdx.x;

    for (int i = t; i < G_GRAPHS * D_DIM; i += 1024) {
        int g = i >> 6;
        int c = start[g + 1] - start[g];
        p[g][i & 63] = pooled[i] / (float)(c > 0 ? c : 1);
    }
    __syncthreads();

    for (int i = t; i < G_GRAPHS * D_DIM; i += 1024) {
        int g = i >> 6, o = i & 63;
        float a = fc1b[o];
#pragma unroll
        for (int d = 0; d < D_DIM; ++d) a = fmaf(p[g][d], fc1w[d * D_DIM + o], a);
        hf[g][o] = fmaxf(a, 0.f);
    }
    __syncthreads();

    if (t < G_GRAPHS * C_CLS) {
        int g = t / C_CLS, c = t % C_CLS;
        float a = fc2b[c];
#pragma unroll
        for (int d = 0; d < D_DIM; ++d) a = fmaf(hf[g][d], fc2w[d * C_CLS + c], a);
        sc[g][c] = a;
    }
    __syncthreads();

    if (t < G_GRAPHS) {
        float m = -1e30f;
#pragma unroll
        for (int c = 0; c < C_CLS; ++c) m = fmaxf(m, sc[t][c]);
        float s = 0.f;
#pragma unroll
        for (int c = 0; c < C_CLS; ++c) s += expf(sc[t][c] - m);
        float lse = m + logf(s);
#pragma unroll
        for (int c = 0; c < C_CLS; ++c) out[t * C_CLS + c] = sc[t][c] - lse;
    }
}

// ---------------- launch ----------------
// ws budget ~182 MB: off 3.2 + srcSorted 16 + perm 3.2 + hb0 25.6 + hb1 25.6 +
// mbuf 102.4 (coarse 17.6 aliased) + wfrag 0.12 + partial 2.1 + small

extern "C" void kernel_launch(void* const* d_in, const int* in_sizes, int n_in,
                              void* d_out, int out_size, void* d_ws, size_t ws_size,
                              hipStream_t stream) {
    const int*   x_op    = (const int*)d_in[0];
    const int*   x_cat   = (const int*)d_in[1];
    const int*   eidx    = (const int*)d_in[2];
    const int*   src     = eidx;
    const int*   tgt     = eidx + N_EDGES;
    const int*   etype   = (const int*)d_in[3];
    const int*   batch   = (const int*)d_in[4];
    const float* op_emb  = (const float*)d_in[5];
    const float* cat_emb = (const float*)d_in[6];
    const float* w1 = (const float*)d_in[7];
    const float* r1 = (const float*)d_in[8];
    const float* b1 = (const float*)d_in[9];
    const float* w2 = (const float*)d_in[10];
    const float* r2 = (const float*)d_in[11];
    const float* b2 = (const float*)d_in[12];
    const float* w3 = (const float*)d_in[13];
    const float* r3 = (const float*)d_in[14];
    const float* b3 = (const float*)d_in[15];
    const float* fc1w = (const float*)d_in[16];
    const float* fc1b = (const float*)d_in[17];
    const float* fc2w = (const float*)d_in[18];
    const float* fc2b = (const float*)d_in[19];
    float* out = (float*)d_out;

    char* ws = (char*)d_ws;
    size_t o = 0;
    auto alloc = [&](size_t bytes) -> void* {
        o = (o + 255) & ~(size_t)255;
        void* p = ws + o;
        o += bytes;
        return p;
    };

    int*   off        = (int*)alloc((size_t)(NR + 1) * 4);
    int*   srcSorted  = (int*)alloc((size_t)N_EDGES * 4);
    int*   perm       = (int*)alloc((size_t)NR * 4);
    unsigned short* hb0   = (unsigned short*)alloc((size_t)N_NODES * D_DIM * 2);
    unsigned short* hb1   = (unsigned short*)alloc((size_t)N_NODES * D_DIM * 2);
    unsigned short* mbuf  = (unsigned short*)alloc((size_t)NR * D_DIM * 2);   // 102.4 MB
    unsigned int*   coarse = (unsigned int*)mbuf;    // 17.6 MB, dead before k_agg
    unsigned short* wfrag = (unsigned short*)alloc((size_t)15 * 4096 * 2);
    float* partial    = (float*)alloc((size_t)POOL_BLOCKS * G_GRAPHS * D_DIM * 4);
    float* pooled     = (float*)alloc((size_t)G_GRAPHS * D_DIM * 4);
    int*   startg     = (int*)alloc((size_t)(G_GRAPHS + 1) * 4);
    int*   zeroReg    = (int*)alloc((size_t)(NCB + 16) * 4);   // gcur | ghist
    int*   gcur       = zeroReg;
    int*   ghist      = zeroReg + NCB;
    int*   classBase  = (int*)alloc(16 * 4);
    int*   blockBase  = (int*)alloc((size_t)391 * 16 * 4);

    hipMemsetAsync(zeroReg, 0, (size_t)(NCB + 16) * 4, stream);

    // CSR build: LDS-staged 2-pass radix (all writes contiguous runs)
    k_coarse<<<(N_EDGES + EPB - 1) / EPB, 512, 0, stream>>>(src, tgt, etype, gcur, coarse);
    k_fine<<<NCB, 1024, 0, stream>>>(gcur, coarse, off, srcSorted);

    // degree-bucketed key permutation
    k_dhist<<<391, 256, 0, stream>>>(off, ghist, blockBase);
    k_dscan<<<1, 64, 0, stream>>>(ghist, classBase);
    k_dperm<<<391, 256, 0, stream>>>(off, classBase, blockBase, perm);

    // embed + bounds + weight prep (fused)
    WPtrs wp;
    wp.p[0] = w1;          wp.p[1] = w1 + 4096;  wp.p[2] = w1 + 8192;  wp.p[3] = w1 + 12288;
    wp.p[4] = r1;
    wp.p[5] = w2;          wp.p[6] = w2 + 4096;  wp.p[7] = w2 + 8192;  wp.p[8] = w2 + 12288;
    wp.p[9] = r2;
    wp.p[10] = w3;         wp.p[11] = w3 + 4096; wp.p[12] = w3 + 8192; wp.p[13] = w3 + 12288;
    wp.p[14] = r3;
    k_misc<<<EMBED_BLOCKS + BOUNDS_BLOCKS + 15, 256, 0, stream>>>(
        x_op, x_cat, (const float4*)op_emb, (const float4*)cat_emb, (ushort4*)hb0,
        batch, startg, wp, wfrag);

    const int aggBlocks  = NR / 8 / 4;           // 25000 (4 waves/block)
    const int gemmBlocks = N_NODES / 64;         // 3125

    // layer 1
    k_agg<<<aggBlocks, 256, 0, stream>>>(hb0, off, srcSorted, perm, mbuf);
    k_trans<1><<<gemmBlocks, 1024, 0, stream>>>(hb0, mbuf, hb1, wfrag, b1);
    // layer 2
    k_agg<<<aggBlocks, 256, 0, stream>>>(hb1, off, srcSorted, perm, mbuf);
    k_trans<1><<<gemmBlocks, 1024, 0, stream>>>(hb1, mbuf, hb0, wfrag + 5 * 4096, b2);
    // layer 3
    k_agg<<<aggBlocks, 256, 0, stream>>>(hb0, off, srcSorted, perm, mbuf);
    k_trans<0><<<gemmBlocks, 1024, 0, stream>>>(hb0, mbuf, hb1, wfrag + 10 * 4096, b3);

    k_pool<<<POOL_BLOCKS, 1024, 0, stream>>>(hb1, batch, partial);
    k_pool_reduce<<<(G_GRAPHS * D_DIM + 255) / 256, 256, 0, stream>>>(partial, pooled);
    k_head<<<1, 1024, 0, stream>>>(pooled, startg, fc1w, fc1b, fc2w, fc2b, out);
}

// Round 12
// 426.745 us; speedup vs baseline: 1.6075x; 1.6075x over previous
//
#include <hip/hip_runtime.h>
#include <hip/hip_bf16.h>

#define N_NODES 200000
#define N_EDGES 4000000
#define R_REL   4
#define D_DIM   64
#define G_GRAPHS 64
#define C_CLS   10
#define NR      (N_NODES * R_REL)      // 800000
#define POOL_BLOCKS 128

// 2-pass radix CSR build
#define NCB   391                       // ceil(NR / 2048) coarse buckets (key>>11)
#define LCAP  64                        // LDS bin cap (lambda=20.9, +9.3 sigma)
#define CCAP  11264                     // coarse bucket cap (lambda=10230, +10 sigma)
#define EPB   8192                      // edges per k_coarse block (512 thr x 16)

#define EMBED_BLOCKS 12500              // N*16/256
#define BOUNDS_BLOCKS 782               // ceil(N/256)

#define MS    72                        // m_lds row stride in shorts (144 B, 16B-aligned pad)

typedef __attribute__((ext_vector_type(8))) short short8v;   // 8 bf16 (4 VGPR)
typedef __attribute__((ext_vector_type(4))) float f32x4;

__device__ __forceinline__ unsigned short to_bf16(float x) {
    __hip_bfloat16 b = __float2bfloat16(x);
    return *(unsigned short*)&b;
}

#define ACC8(u) \
    a0 += __uint_as_float((u).x << 16); \
    a1 += __uint_as_float((u).x & 0xFFFF0000u); \
    a2 += __uint_as_float((u).y << 16); \
    a3 += __uint_as_float((u).y & 0xFFFF0000u); \
    a4 += __uint_as_float((u).z << 16); \
    a5 += __uint_as_float((u).z & 0xFFFF0000u); \
    a6 += __uint_as_float((u).w << 16); \
    a7 += __uint_as_float((u).w & 0xFFFF0000u);

// ---------------- CSR build pass 1: LDS-staged coarse binning ----------------
// entry = (key & 2047) << 18 | src   (11 + 18 bits)

__global__ __launch_bounds__(512) void k_coarse(
    const int* __restrict__ src, const int* __restrict__ tgt,
    const int* __restrict__ et,
    int* __restrict__ gcur, unsigned int* __restrict__ coarse) {
    __shared__ unsigned int bins[NCB * LCAP];   // 100 KB
    __shared__ int lcnt[NCB], lpos[NCB];

    const int tid = threadIdx.x;
    for (int i = tid; i < NCB; i += 512) lcnt[i] = 0;
    __syncthreads();

#pragma unroll
    for (int h = 0; h < 4; ++h) {
        int e4 = blockIdx.x * EPB + (h * 512 + tid) * 4;
        if (e4 < N_EDGES) {
            int4 s = *(const int4*)&src[e4];
            int4 t = *(const int4*)&tgt[e4];
            int4 r = *(const int4*)&et[e4];
#define PUT(ss, tt, rr) { \
                int key = (tt) * R_REL + (rr); \
                int b = key >> 11; \
                int p = atomicAdd(&lcnt[b], 1); \
                if (p < LCAP) bins[b * LCAP + p] = \
                    ((unsigned int)(key & 2047) << 18) | (unsigned int)(ss); \
            }
            PUT(s.x, t.x, r.x); PUT(s.y, t.y, r.y);
            PUT(s.z, t.z, r.z); PUT(s.w, t.w, r.w);
#undef PUT
        }
    }
    __syncthreads();

    for (int i = tid; i < NCB; i += 512) {
        int c = lcnt[i]; if (c > LCAP) c = LCAP;
        lcnt[i] = c;
        lpos[i] = atomicAdd(&gcur[i], c);
    }
    __syncthreads();

    for (int j = tid; j < NCB * LCAP; j += 512) {
        int b = j >> 6, l = j & 63;
        if (l < lcnt[b]) {
            int gp = lpos[b] + l;
            if (gp < CCAP) coarse[(size_t)b * CCAP + gp] = bins[j];
        }
    }
}

// ---------------- CSR build pass 2: per-bucket fine counting sort ----------------

__global__ __launch_bounds__(1024) void k_fine(
    const int* __restrict__ gcur, const unsigned int* __restrict__ coarse,
    int* __restrict__ off, int* __restrict__ srcSorted) {
    __shared__ unsigned int ent[CCAP];   // 45 KB
    __shared__ int hist[2048];           // 8 KB
    __shared__ int pre[512];             // 2 KB

    const int cb = blockIdx.x, tid = threadIdx.x;

    // inclusive scan of clamped gcur over 512 slots -> base for this bucket
    int v = 0;
    if (tid < 512) {
        v = (tid < NCB) ? gcur[tid] : 0;
        if (v > CCAP) v = CCAP;
        pre[tid] = v;
    }
    __syncthreads();
    for (int d = 1; d < 512; d <<= 1) {
        int t = 0;
        if (tid < 512 && tid >= d) t = pre[tid - d];
        __syncthreads();
        if (tid < 512) pre[tid] += t;
        __syncthreads();
    }
    const int gb = (cb > 0) ? pre[cb - 1] : 0;

    int cnt = gcur[cb]; if (cnt > CCAP) cnt = CCAP;
    const int key0 = cb << 11;
    const unsigned int* cp = coarse + (size_t)cb * CCAP;

    for (int i = tid; i < cnt; i += 1024) ent[i] = cp[i];
    hist[tid] = 0; hist[tid + 1024] = 0;
    __syncthreads();

    for (int i = tid; i < cnt; i += 1024) atomicAdd(&hist[ent[i] >> 18], 1);
    __syncthreads();

    int x0 = hist[tid], x1 = hist[tid + 1024];
    for (int d = 1; d < 2048; d <<= 1) {
        int v0 = (tid >= d) ? hist[tid - d] : 0;
        int v1 = hist[tid + 1024 - d];
        __syncthreads();
        hist[tid] += v0;
        hist[tid + 1024] += v1;
        __syncthreads();
    }
    int excl0 = hist[tid] - x0;
    int excl1 = hist[tid + 1024] - x1;
    __syncthreads();
    hist[tid] = excl0;                   // becomes scatter cursor
    hist[tid + 1024] = excl1;

    int key = key0 + tid;
    if (key < NR) off[key] = gb + excl0;
    key = key0 + tid + 1024;
    if (key < NR) off[key] = gb + excl1;
    if (cb == NCB - 1 && tid == 0) off[NR] = N_EDGES;
    __syncthreads();

    for (int i = tid; i < cnt; i += 1024) {
        unsigned int e = ent[i];
        int pos = atomicAdd(&hist[e >> 18], 1);
        srcSorted[gb + pos] = (int)(e & 0x3FFFFu);
    }
}

// ---------------- fused misc: embed + bounds + weight prep ----------------

struct WPtrs { const float* p[15]; };

__global__ void k_misc(const int* __restrict__ xop, const int* __restrict__ xcat,
                       const float4* __restrict__ opemb, const float4* __restrict__ catemb,
                       ushort4* __restrict__ hb,
                       const int* __restrict__ batch, int* __restrict__ start,
                       WPtrs wp, unsigned short* __restrict__ wfrag) {
    int bid = blockIdx.x;
    if (bid < EMBED_BLOCKS) {
        int i = bid * 256 + threadIdx.x;
        if (i < N_NODES * 16) {
            int n = i >> 4, q = i & 15;
            float4 a = opemb[xop[n] * 16 + q];
            float4 b = catemb[xcat[n] * 16 + q];
            ushort4 ub;
            ub.x = to_bf16(a.x + b.x); ub.y = to_bf16(a.y + b.y);
            ub.z = to_bf16(a.z + b.z); ub.w = to_bf16(a.w + b.w);
            hb[i] = ub;
        }
    } else if (bid < EMBED_BLOCKS + BOUNDS_BLOCKS) {
        int i = (bid - EMBED_BLOCKS) * 256 + threadIdx.x;
        if (i >= N_NODES) return;
        int b = batch[i];
        if (i == 0) {
            for (int g = 0; g <= b; ++g) start[g] = 0;
        } else {
            int p = batch[i - 1];
            for (int g = p + 1; g <= b; ++g) start[g] = i;
        }
        if (i == N_NODES - 1) {
            for (int g = b + 1; g <= G_GRAPHS; ++g) start[g] = N_NODES;
        }
    } else {
        int m = bid - EMBED_BLOCKS - BOUNDS_BLOCKS;    // 0..14
        const float* W = wp.p[m];
        unsigned short* outp = wfrag + m * 4096;
        for (int f = threadIdx.x; f < 4096; f += 256) {
            int j = f & 7, lane = (f >> 3) & 63, c0t = (f >> 9) & 3, kk = f >> 11;
            int k  = kk * 32 + (lane >> 4) * 8 + j;
            int ch = c0t * 16 + (lane & 15);
            outp[f] = to_bf16(W[k * 64 + ch]);
        }
    }
}

// ---------------- fused RGCN layer: gather-aggregate (LDS m tile) + MFMA ----------------
// Block = 1024 threads (16 waves), 64 nodes = 256 keys.
// Phase A: wave w aggregates keys [w*16, w*16+16) in two 8-key register passes
//   (lane = (g=lane>>3 key-group, q=lane&7 channel octet); one dwordx4 per lane
//   covers 8 edges' full 128B rows; 4-deep unroll); means stored bf16 into
//   m_lds [256][MS=72] (pad kills the stride-128 bank pathology; <=8-way ok).
// Phase B: MFMA 16x16x32: wave (nt=wid>>2, ct=wid&3) computes node tile x ch tile;
//   A-frags from m_lds (r<4) / hb_in (root), B-frags from wf. C/D mapping per r8.

template <int RELU>
__global__ __launch_bounds__(1024, 2) void k_layer(
    const unsigned short* __restrict__ hb_in,  // [N][64] bf16
    unsigned short* __restrict__ hb_out,       // [N][64] bf16
    const int* __restrict__ off, const int* __restrict__ srcSorted,
    const unsigned short* __restrict__ wfrag,  // this layer: [5][2][4][64][8] bf16
    const float* __restrict__ bias)            // [64]
{
    __shared__ unsigned short m_lds[256 * MS]; // 36864 B
    __shared__ unsigned short wf[5 * 4096];    // 40960 B

    const int tid  = threadIdx.x;
    const int lane = tid & 63, wid = tid >> 6;
    const int g = lane >> 3, q = lane & 7;
    const int nbase = blockIdx.x * 64;

    // stage weights (consumed after the phase-A barrier)
    for (int i = tid; i < 2560; i += 1024)
        ((uint4*)wf)[i] = ((const uint4*)wfrag)[i];

    // ---- phase A: aggregate 16 keys per wave into m_lds ----
    const unsigned short* base = hb_in + q * 8;
#pragma unroll
    for (int p = 0; p < 2; ++p) {
        const int keyLocal = wid * 16 + p * 8 + g;
        const int key = nbase * R_REL + keyLocal;
        const int e0 = off[key];
        const int e1 = off[key + 1];

        float a0 = 0.f, a1 = 0.f, a2 = 0.f, a3 = 0.f,
              a4 = 0.f, a5 = 0.f, a6 = 0.f, a7 = 0.f;

        int e = e0;
        for (; e + 4 <= e1; e += 4) {
            int s0 = srcSorted[e];
            int s1 = srcSorted[e + 1];
            int s2 = srcSorted[e + 2];
            int s3 = srcSorted[e + 3];
            uint4 u0 = *(const uint4*)(base + (size_t)s0 * D_DIM);
            uint4 u1 = *(const uint4*)(base + (size_t)s1 * D_DIM);
            uint4 u2 = *(const uint4*)(base + (size_t)s2 * D_DIM);
            uint4 u3 = *(const uint4*)(base + (size_t)s3 * D_DIM);
            ACC8(u0); ACC8(u1); ACC8(u2); ACC8(u3);
        }
        for (; e < e1; ++e) {
            int s0 = srcSorted[e];
            uint4 u0 = *(const uint4*)(base + (size_t)s0 * D_DIM);
            ACC8(u0);
        }

        int deg = e1 - e0;
        const float iv = 1.0f / (float)(deg > 0 ? deg : 1);
        uint4 o;
        o.x = (unsigned int)to_bf16(a0 * iv) | ((unsigned int)to_bf16(a1 * iv) << 16);
        o.y = (unsigned int)to_bf16(a2 * iv) | ((unsigned int)to_bf16(a3 * iv) << 16);
        o.z = (unsigned int)to_bf16(a4 * iv) | ((unsigned int)to_bf16(a5 * iv) << 16);
        o.w = (unsigned int)to_bf16(a6 * iv) | ((unsigned int)to_bf16(a7 * iv) << 16);
        *(uint4*)(&m_lds[keyLocal * MS + q * 8]) = o;
    }
    __syncthreads();

    // ---- phase B: MFMA ----
    const int n0 = (wid >> 2) * 16;            // local node tile base
    const int ct = wid & 3;                    // out-ch tile
    const int arowL = n0 + (lane & 15);        // local node of A row
    const int koff = (lane >> 4) * 8;          // bf16 element offset in k-block

    f32x4 acc = {0.f, 0.f, 0.f, 0.f};

#pragma unroll
    for (int r = 0; r < 5; ++r) {
        uint4 a0u, a1u;
        if (r < 4) {
            const unsigned short* ap = &m_lds[(arowL * R_REL + r) * MS];
            a0u = *(const uint4*)(ap + koff);
            a1u = *(const uint4*)(ap + 32 + koff);
        } else {
            const unsigned short* ap = hb_in + (size_t)(nbase + arowL) * D_DIM;
            a0u = *(const uint4*)(ap + koff);
            a1u = *(const uint4*)(ap + 32 + koff);
        }
        const unsigned short* bbase = wf + r * 4096 + ct * 512 + lane * 8;
        uint4 b0u = *(const uint4*)bbase;                // kk=0
        uint4 b1u = *(const uint4*)(bbase + 2048);       // kk=1
        acc = __builtin_amdgcn_mfma_f32_16x16x32_bf16(
            __builtin_bit_cast(short8v, a0u), __builtin_bit_cast(short8v, b0u), acc, 0, 0, 0);
        acc = __builtin_amdgcn_mfma_f32_16x16x32_bf16(
            __builtin_bit_cast(short8v, a1u), __builtin_bit_cast(short8v, b1u), acc, 0, 0, 0);
    }

    float bv = bias[ct * 16 + (lane & 15)];
#pragma unroll
    for (int i = 0; i < 4; ++i) {
        float v = acc[i] + bv;
        if (RELU) v = fmaxf(v, 0.f);
        int n = nbase + n0 + (lane >> 4) * 4 + i;
        hb_out[(size_t)n * D_DIM + ct * 16 + (lane & 15)] = to_bf16(v);
    }
}

// ---------------- pooling: run-accumulated (batch is sorted), bf16 input ----------------

__global__ __launch_bounds__(1024) void k_pool(const unsigned short* __restrict__ hb,
                                               const int* __restrict__ batch,
                                               float* __restrict__ partial) {
    __shared__ float bin[G_GRAPHS * D_DIM];   // 16 KB
    int tid = threadIdx.x, lane = tid & 63, wid = tid >> 6;
    for (int i = tid; i < G_GRAPHS * D_DIM; i += 1024) bin[i] = 0.f;
    __syncthreads();
    const int per = (N_NODES + POOL_BLOCKS - 1) / POOL_BLOCKS;
    int n0 = blockIdx.x * per;
    int n1 = n0 + per; if (n1 > N_NODES) n1 = N_NODES;
    int cntw = n1 - n0;
    int sub = (cntw + 15) >> 4;
    int w0 = n0 + wid * sub;
    int w1 = w0 + sub; if (w1 > n1) w1 = n1;

    float acc = 0.f;
    int cur = -1;
    for (int n = w0; n < w1; ++n) {
        int b = __builtin_amdgcn_readfirstlane(batch[n]);
        unsigned int u = hb[(size_t)n * D_DIM + lane];
        float v = __uint_as_float(u << 16);
        if (b != cur) {
            if (cur >= 0) atomicAdd(&bin[cur * D_DIM + lane], acc);
            cur = b;
            acc = v;
        } else {
            acc += v;
        }
    }
    if (cur >= 0) atomicAdd(&bin[cur * D_DIM + lane], acc);
    __syncthreads();
    for (int i = tid; i < G_GRAPHS * D_DIM; i += 1024)
        partial[blockIdx.x * (G_GRAPHS * D_DIM) + i] = bin[i];
}

__global__ void k_pool_reduce(const float* __restrict__ partial,
                              float* __restrict__ pooled) {
    int i = blockIdx.x * blockDim.x + threadIdx.x;   // 4096
    if (i < G_GRAPHS * D_DIM) {
        float s = 0.f;
        for (int b = 0; b < POOL_BLOCKS; ++b) s += partial[b * (G_GRAPHS * D_DIM) + i];
        pooled[i] = s;
    }
}

// ---------------- head ----------------

__global__ void k_head(const float* __restrict__ pooled, const int* __restrict__ start,
                       const float* __restrict__ fc1w, const float* __restrict__ fc1b,
                       const float* __restrict__ fc2w, const float* __restrict__ fc2b,
                       float* __restrict__ out) {
    __shared__ float p[G_GRAPHS][D_DIM];
    __shared__ float hf[G_GRAPHS][D_DIM];
    __shared__ float sc[G_GRAPHS][C_CLS];
    int t = threadIdx.x;

    for (int i = t; i < G_GRAPHS * D_DIM; i += 1024) {
        int g = i >> 6;
        int c = start[g + 1] - start[g];
        p[g][i & 63] = pooled[i] / (float)(c > 0 ? c : 1);
    }
    __syncthreads();

    for (int i = t; i < G_GRAPHS * D_DIM; i += 1024) {
        int g = i >> 6, o = i & 63;
        float a = fc1b[o];
#pragma unroll
        for (int d = 0; d < D_DIM; ++d) a = fmaf(p[g][d], fc1w[d * D_DIM + o], a);
        hf[g][o] = fmaxf(a, 0.f);
    }
    __syncthreads();

    if (t < G_GRAPHS * C_CLS) {
        int g = t / C_CLS, c = t % C_CLS;
        float a = fc2b[c];
#pragma unroll
        for (int d = 0; d < D_DIM; ++d) a = fmaf(hf[g][d], fc2w[d * C_CLS + c], a);
        sc[g][c] = a;
    }
    __syncthreads();

    if (t < G_GRAPHS) {
        float m = -1e30f;
#pragma unroll
        for (int c = 0; c < C_CLS; ++c) m = fmaxf(m, sc[t][c]);
        float s = 0.f;
#pragma unroll
        for (int c = 0; c < C_CLS; ++c) s += expf(sc[t][c] - m);
        float lse = m + logf(s);
#pragma unroll
        for (int c = 0; c < C_CLS; ++c) out[t * C_CLS + c] = sc[t][c] - lse;
    }
}

// ---------------- launch ----------------
// ws budget ~90 MB: off 3.2 + srcSorted 16 + hb0 25.6 + hb1 25.6 + coarse 17.6 +
// wfrag 0.12 + partial 2.1 + small

extern "C" void kernel_launch(void* const* d_in, const int* in_sizes, int n_in,
                              void* d_out, int out_size, void* d_ws, size_t ws_size,
                              hipStream_t stream) {
    const int*   x_op    = (const int*)d_in[0];
    const int*   x_cat   = (const int*)d_in[1];
    const int*   eidx    = (const int*)d_in[2];
    const int*   src     = eidx;
    const int*   tgt     = eidx + N_EDGES;
    const int*   etype   = (const int*)d_in[3];
    const int*   batch   = (const int*)d_in[4];
    const float* op_emb  = (const float*)d_in[5];
    const float* cat_emb = (const float*)d_in[6];
    const float* w1 = (const float*)d_in[7];
    const float* r1 = (const float*)d_in[8];
    const float* b1 = (const float*)d_in[9];
    const float* w2 = (const float*)d_in[10];
    const float* r2 = (const float*)d_in[11];
    const float* b2 = (const float*)d_in[12];
    const float* w3 = (const float*)d_in[13];
    const float* r3 = (const float*)d_in[14];
    const float* b3 = (const float*)d_in[15];
    const float* fc1w = (const float*)d_in[16];
    const float* fc1b = (const float*)d_in[17];
    const float* fc2w = (const float*)d_in[18];
    const float* fc2b = (const float*)d_in[19];
    float* out = (float*)d_out;

    char* ws = (char*)d_ws;
    size_t o = 0;
    auto alloc = [&](size_t bytes) -> void* {
        o = (o + 255) & ~(size_t)255;
        void* p = ws + o;
        o += bytes;
        return p;
    };

    int*   off        = (int*)alloc((size_t)(NR + 1) * 4);
    int*   srcSorted  = (int*)alloc((size_t)N_EDGES * 4);
    unsigned short* hb0   = (unsigned short*)alloc((size_t)N_NODES * D_DIM * 2);
    unsigned short* hb1   = (unsigned short*)alloc((size_t)N_NODES * D_DIM * 2);
    unsigned int*   coarse = (unsigned int*)alloc((size_t)NCB * CCAP * 4);   // 17.6 MB
    unsigned short* wfrag = (unsigned short*)alloc((size_t)15 * 4096 * 2);
    float* partial    = (float*)alloc((size_t)POOL_BLOCKS * G_GRAPHS * D_DIM * 4);
    float* pooled     = (float*)alloc((size_t)G_GRAPHS * D_DIM * 4);
    int*   startg     = (int*)alloc((size_t)(G_GRAPHS + 1) * 4);
    int*   gcur       = (int*)alloc((size_t)NCB * 4);

    hipMemsetAsync(gcur, 0, (size_t)NCB * 4, stream);

    // CSR build: LDS-staged 2-pass radix (all writes contiguous runs)
    k_coarse<<<(N_EDGES + EPB - 1) / EPB, 512, 0, stream>>>(src, tgt, etype, gcur, coarse);
    k_fine<<<NCB, 1024, 0, stream>>>(gcur, coarse, off, srcSorted);

    // embed + bounds + weight prep (fused)
    WPtrs wp;
    wp.p[0] = w1;          wp.p[1] = w1 + 4096;  wp.p[2] = w1 + 8192;  wp.p[3] = w1 + 12288;
    wp.p[4] = r1;
    wp.p[5] = w2;          wp.p[6] = w2 + 4096;  wp.p[7] = w2 + 8192;  wp.p[8] = w2 + 12288;
    wp.p[9] = r2;
    wp.p[10] = w3;         wp.p[11] = w3 + 4096; wp.p[12] = w3 + 8192; wp.p[13] = w3 + 12288;
    wp.p[14] = r3;
    k_misc<<<EMBED_BLOCKS + BOUNDS_BLOCKS + 15, 256, 0, stream>>>(
        x_op, x_cat, (const float4*)op_emb, (const float4*)cat_emb, (ushort4*)hb0,
        batch, startg, wp, wfrag);

    const int layerBlocks = N_NODES / 64;        // 3125

    k_layer<1><<<layerBlocks, 1024, 0, stream>>>(hb0, hb1, off, srcSorted, wfrag, b1);
    k_layer<1><<<layerBlocks, 1024, 0, stream>>>(hb1, hb0, off, srcSorted, wfrag + 5 * 4096, b2);
    k_layer<0><<<layerBlocks, 1024, 0, stream>>>(hb0, hb1, off, srcSorted, wfrag + 10 * 4096, b3);

    k_pool<<<POOL_BLOCKS, 1024, 0, stream>>>(hb1, batch, partial);
    k_pool_reduce<<<(G_GRAPHS * D_DIM + 255) / 256, 256, 0, stream>>>(partial, pooled);
    k_head<<<1, 1024, 0, stream>>>(pooled, startg, fc1w, fc1b, fc2w, fc2b, out);
}